// Round 2
// baseline (327.141 us; speedup 1.0000x reference)
//
#include <hip/hip_runtime.h>
#include <cstdint>
#include <cstddef>

#define NB 8
#define NG 64
#define NP 50000

__device__ __forceinline__ void opaque(float& x) { asm volatile("" : "+v"(x)); }

__global__ __launch_bounds__(256) void iou_main(
    const float* __restrict__ pred,
    const float* __restrict__ gt,
    float* __restrict__ out_iou,
    float* __restrict__ out_pos,
    float* __restrict__ out_neg,
    unsigned long long* __restrict__ keys)
{
    __shared__ float s_gx0[NG], s_gy0[NG], s_gx1[NG], s_gy1[NG], s_ga[NG];
    const int b = blockIdx.y;
    const int tid = threadIdx.x;

    if (tid < NG) {
        const float4 gb = reinterpret_cast<const float4*>(gt)[b * NG + tid];
        float hw = 0.5f * gb.z, hh = 0.5f * gb.w;   // exact (x0.5), FMA-safe
        float x0 = gb.x - hw, y0 = gb.y - hh;
        float x1 = gb.x + hw, y1 = gb.y + hh;
        float ga = (x1 - x0) * (y1 - y0);
        opaque(ga);                                  // block FMA contraction into sums
        s_gx0[tid] = x0; s_gy0[tid] = y0;
        s_gx1[tid] = x1; s_gy1[tid] = y1;
        s_ga[tid]  = ga;
    }
    __syncthreads();

    const int p = blockIdx.x * blockDim.x + tid;
    const bool active = p < NP;
    const int pc = active ? p : (NP - 1);

    const float4 pb = reinterpret_cast<const float4*>(pred)[(size_t)b * NP + pc];
    float hw = 0.5f * pb.z, hh = 0.5f * pb.w;
    const float px0 = pb.x - hw, py0 = pb.y - hh;
    const float px1 = pb.x + hw, py1 = pb.y + hh;
    float pa = (px1 - px0) * (py1 - py0);
    opaque(pa);

    float maxv = 0.0f;
    float* pi = out_iou + (size_t)b * NG * NP + p;
    float* pp = out_pos + (size_t)b * NG * NP + p;
    const int lane = tid & 63;
    const unsigned int wave_base_p = (unsigned int)(blockIdx.x * blockDim.x + (tid & ~63));

    for (int g = 0; g < NG; ++g) {
        float lx = fmaxf(s_gx0[g], px0);
        float ly = fmaxf(s_gy0[g], py0);
        float rx = fminf(s_gx1[g], px1);
        float ry = fminf(s_gy1[g], py1);
        float wx = fmaxf(rx - lx, 0.0f);
        float wy = fmaxf(ry - ly, 0.0f);
        float inter = wx * wy;
        opaque(inter);                               // keep numpy op order: (ga+pa)-inter
        float denom = (s_ga[g] + pa) - inter;
        float iou = inter / denom;                   // IEEE div, matches numpy

        if (active) {
            pi[(size_t)g * NP] = iou;
            pp[(size_t)g * NP] = (iou > 0.7f) ? 1.0f : 0.0f;
            maxv = fmaxf(maxv, iou);
        }

        // wave-level argmax over p for this g (first-occurrence tie-break)
        float r = active ? iou : -1.0f;
        float wmax = r;
        #pragma unroll
        for (int s = 1; s < 64; s <<= 1)
            wmax = fmaxf(wmax, __shfl_xor(wmax, s, 64));
        if (wmax >= 0.0f) {                          // wave-uniform (some lane active)
            unsigned long long m = __ballot(r == wmax);
            int fl = __ffsll(m) - 1;                 // lowest lane == lowest p
            if (lane == 0) {
                unsigned int pw = wave_base_p + (unsigned int)fl;
                unsigned long long key =
                    ((unsigned long long)__float_as_uint(wmax) << 32) |
                    (unsigned long long)(0xFFFFFFFFu - pw);
                atomicMax(&keys[b * NG + g], key);
            }
        }
    }

    if (active) {
        out_neg[(size_t)b * NP + p] = (maxv < 0.3f) ? 1.0f : 0.0f;
    }
}

__global__ void fixup_pos(const unsigned long long* __restrict__ keys,
                          float* __restrict__ out_pos)
{
    int i = blockIdx.x * blockDim.x + threadIdx.x;
    if (i < NB * NG) {
        unsigned long long k = keys[i];
        unsigned int idx = 0xFFFFFFFFu - (unsigned int)(k & 0xFFFFFFFFull);
        if (idx < NP) out_pos[(size_t)i * NP + idx] = 1.0f;
    }
}

extern "C" void kernel_launch(void* const* d_in, const int* in_sizes, int n_in,
                              void* d_out, int out_size, void* d_ws, size_t ws_size,
                              hipStream_t stream) {
    const float* pred = (const float*)d_in[0];
    const float* gt   = (const float*)d_in[1];
    float* out_iou = (float*)d_out;
    float* out_pos = out_iou + (size_t)NB * NG * NP;
    float* out_neg = out_pos + (size_t)NB * NG * NP;
    unsigned long long* keys = (unsigned long long*)d_ws;

    hipMemsetAsync(keys, 0, NB * NG * sizeof(unsigned long long), stream);

    dim3 grid((NP + 255) / 256, NB);
    iou_main<<<grid, dim3(256), 0, stream>>>(pred, gt, out_iou, out_pos, out_neg, keys);
    fixup_pos<<<1, 512, 0, stream>>>(keys, out_pos);
}

// Round 3
// 60.537 us; speedup vs baseline: 5.4040x; 5.4040x over previous
//
#include <hip/hip_runtime.h>
#include <cstdint>
#include <cstddef>

#define NB 8
#define NG 64
#define NP 50000

__device__ __forceinline__ void opaque(float& x) { asm volatile("" : "+v"(x)); }

// Kernel 1: pure streaming — iou, pos (threshold part), neg. No shuffles, no atomics.
// Each thread owns 2 consecutive preds. Grid: (ceil(25000/256)=98, 8) = 784 blocks.
__global__ __launch_bounds__(256) void iou_main(
    const float* __restrict__ pred,
    const float* __restrict__ gt,
    float* __restrict__ out_iou,
    float* __restrict__ out_pos,
    float* __restrict__ out_neg)
{
    __shared__ float s_gx0[NG], s_gy0[NG], s_gx1[NG], s_gy1[NG], s_ga[NG];
    const int b = blockIdx.y;
    const int tid = threadIdx.x;

    if (tid < NG) {
        const float4 gb = reinterpret_cast<const float4*>(gt)[b * NG + tid];
        float hw = 0.5f * gb.z, hh = 0.5f * gb.w;   // exact, FMA-safe
        float x0 = gb.x - hw, y0 = gb.y - hh;
        float x1 = gb.x + hw, y1 = gb.y + hh;
        float ga = (x1 - x0) * (y1 - y0);
        opaque(ga);                                  // block FMA contraction into sums
        s_gx0[tid] = x0; s_gy0[tid] = y0;
        s_gx1[tid] = x1; s_gy1[tid] = y1;
        s_ga[tid]  = ga;
    }
    __syncthreads();

    const int p = 2 * (blockIdx.x * blockDim.x + tid);
    if (p >= NP) return;                             // no barriers after this point

    const float4 pb0 = reinterpret_cast<const float4*>(pred)[(size_t)b * NP + p];
    const float4 pb1 = reinterpret_cast<const float4*>(pred)[(size_t)b * NP + p + 1];

    float hw0 = 0.5f * pb0.z, hh0 = 0.5f * pb0.w;
    const float ax0 = pb0.x - hw0, ay0 = pb0.y - hh0;
    const float ax1 = pb0.x + hw0, ay1 = pb0.y + hh0;
    float pa0 = (ax1 - ax0) * (ay1 - ay0);
    opaque(pa0);

    float hw1 = 0.5f * pb1.z, hh1 = 0.5f * pb1.w;
    const float bx0 = pb1.x - hw1, by0 = pb1.y - hh1;
    const float bx1 = pb1.x + hw1, by1 = pb1.y + hh1;
    float pa1 = (bx1 - bx0) * (by1 - by0);
    opaque(pa1);

    float maxv0 = 0.0f, maxv1 = 0.0f;
    const size_t base = (size_t)b * NG * NP + p;

    #pragma unroll 8
    for (int g = 0; g < NG; ++g) {
        const float gx0 = s_gx0[g], gy0 = s_gy0[g];
        const float gx1 = s_gx1[g], gy1 = s_gy1[g];
        const float ga  = s_ga[g];

        float w0 = fmaxf(fminf(gx1, ax1) - fmaxf(gx0, ax0), 0.0f);
        float h0 = fmaxf(fminf(gy1, ay1) - fmaxf(gy0, ay0), 0.0f);
        float inter0 = w0 * h0;
        opaque(inter0);                              // numpy op order: (ga+pa)-inter
        float iou0 = inter0 / ((ga + pa0) - inter0); // IEEE div

        float w1 = fmaxf(fminf(gx1, bx1) - fmaxf(gx0, bx0), 0.0f);
        float h1 = fmaxf(fminf(gy1, by1) - fmaxf(gy0, by0), 0.0f);
        float inter1 = w1 * h1;
        opaque(inter1);
        float iou1 = inter1 / ((ga + pa1) - inter1);

        float2 vi; vi.x = iou0; vi.y = iou1;
        *reinterpret_cast<float2*>(out_iou + base + (size_t)g * NP) = vi;

        float2 vp; vp.x = (iou0 > 0.7f) ? 1.0f : 0.0f;
                   vp.y = (iou1 > 0.7f) ? 1.0f : 0.0f;
        *reinterpret_cast<float2*>(out_pos + base + (size_t)g * NP) = vp;

        maxv0 = fmaxf(maxv0, iou0);
        maxv1 = fmaxf(maxv1, iou1);
    }

    float2 vn; vn.x = (maxv0 < 0.3f) ? 1.0f : 0.0f;
               vn.y = (maxv1 < 0.3f) ? 1.0f : 0.0f;
    *reinterpret_cast<float2*>(out_neg + (size_t)b * NP + p) = vn;
}

// Kernel 2: one block per (b,g) row. Re-read the iou row, block-wide argmax
// (first-occurrence tie-break), OR 1.0 into pos_mask at the winner.
__global__ __launch_bounds__(256) void argmax_fix(
    const float* __restrict__ out_iou,
    float* __restrict__ out_pos)
{
    const int row = blockIdx.x;                      // b*NG + g
    const float4* r4 = reinterpret_cast<const float4*>(out_iou + (size_t)row * NP);

    float bv = -1.0f;
    int   bi = 0x7fffffff;
    for (int c = threadIdx.x; c < NP / 4; c += 256) {
        float4 v = r4[c];
        int p = 4 * c;
        if (v.x > bv) { bv = v.x; bi = p; }          // ascending p per thread:
        if (v.y > bv) { bv = v.y; bi = p + 1; }      // strict > keeps first occurrence
        if (v.z > bv) { bv = v.z; bi = p + 2; }
        if (v.w > bv) { bv = v.w; bi = p + 3; }
    }

    #pragma unroll
    for (int s = 1; s < 64; s <<= 1) {
        float ov = __shfl_xor(bv, s, 64);
        int   oi = __shfl_xor(bi, s, 64);
        if (ov > bv || (ov == bv && oi < bi)) { bv = ov; bi = oi; }
    }

    __shared__ float sv[4];
    __shared__ int   si[4];
    const int wid = threadIdx.x >> 6;
    if ((threadIdx.x & 63) == 0) { sv[wid] = bv; si[wid] = bi; }
    __syncthreads();

    if (threadIdx.x == 0) {
        for (int w = 1; w < 4; ++w)
            if (sv[w] > bv || (sv[w] == bv && si[w] < bi)) { bv = sv[w]; bi = si[w]; }
        out_pos[(size_t)row * NP + bi] = 1.0f;
    }
}

extern "C" void kernel_launch(void* const* d_in, const int* in_sizes, int n_in,
                              void* d_out, int out_size, void* d_ws, size_t ws_size,
                              hipStream_t stream) {
    const float* pred = (const float*)d_in[0];
    const float* gt   = (const float*)d_in[1];
    float* out_iou = (float*)d_out;
    float* out_pos = out_iou + (size_t)NB * NG * NP;
    float* out_neg = out_pos + (size_t)NB * NG * NP;

    dim3 grid1((NP / 2 + 255) / 256, NB);
    iou_main<<<grid1, dim3(256), 0, stream>>>(pred, gt, out_iou, out_pos, out_neg);

    argmax_fix<<<dim3(NB * NG), dim3(256), 0, stream>>>(out_iou, out_pos);
}